// Round 7
// baseline (623.373 us; speedup 1.0000x reference)
//
#include <hip/hip_runtime.h>
#include <hip/hip_bf16.h>

// Problem constants
constexpr int NB  = 4;     // batch
constexpr int NS  = 2048;  // sequence
constexpr int NH  = 8;     // heads
constexpr int DM  = 512;   // d_model
constexpr int DKV = 64;    // d_k = d_v
constexpr int HB  = NH * NB; // 32 (h,b) slices

typedef __attribute__((ext_vector_type(8))) short short8;
typedef __attribute__((ext_vector_type(4))) float f32x4;

__device__ inline unsigned short f2bf(float f) {
    unsigned u = __builtin_bit_cast(unsigned, f);
    u = (u + 0x7fffu + ((u >> 16) & 1u)) >> 16;   // RNE, finite inputs
    return (unsigned short)u;
}
__device__ inline float bf2f(unsigned short h) {
    unsigned u = ((unsigned)h) << 16;
    return __builtin_bit_cast(float, u);
}
__device__ inline short8 ld8(const unsigned short* p) { return *(const short8*)p; }

// Load 8 consecutive fp32, convert to bf16x8 fragment
__device__ inline short8 pack8(const float* p) {
    f32x4 a = *(const f32x4*)p;
    f32x4 b = *(const f32x4*)(p + 4);
    short8 r;
    r[0] = (short)f2bf(a[0]); r[1] = (short)f2bf(a[1]);
    r[2] = (short)f2bf(a[2]); r[3] = (short)f2bf(a[3]);
    r[4] = (short)f2bf(b[0]); r[5] = (short)f2bf(b[1]);
    r[6] = (short)f2bf(b[2]); r[7] = (short)f2bf(b[3]);
    return r;
}

__device__ inline f32x4 mfma16(short8 a, short8 b, f32x4 c) {
    return __builtin_amdgcn_mfma_f32_16x16x32_bf16(a, b, c, 0, 0, 0);
}

// ---------------------------------------------------------------------------
// Convert fp32 -> bf16: y<3: activations q/k/v (4M elems each, 2048 blocks);
// y==3: the four 512x512 weight matrices (128 blocks each, 512 total).
// ---------------------------------------------------------------------------
__global__ __launch_bounds__(256) void k_cvt(const float* __restrict__ x0,
                                             const float* __restrict__ x1,
                                             const float* __restrict__ x2,
                                             const float* __restrict__ w0,
                                             const float* __restrict__ w1,
                                             const float* __restrict__ w2,
                                             const float* __restrict__ w3,
                                             unsigned short* __restrict__ dx0,
                                             unsigned short* __restrict__ dx1,
                                             unsigned short* __restrict__ dx2,
                                             unsigned short* __restrict__ dw0,
                                             unsigned short* __restrict__ dw1,
                                             unsigned short* __restrict__ dw2,
                                             unsigned short* __restrict__ dw3)
{
    const float* s; unsigned short* d; size_t i;
    if (blockIdx.y < 3) {
        switch (blockIdx.y) {
            case 0:  s = x0; d = dx0; break;
            case 1:  s = x1; d = dx1; break;
            default: s = x2; d = dx2; break;
        }
        i = ((size_t)blockIdx.x * 256 + threadIdx.x) * 8;
    } else {
        if (blockIdx.x >= 512) return;
        switch (blockIdx.x >> 7) {
            case 0:  s = w0; d = dw0; break;
            case 1:  s = w1; d = dw1; break;
            case 2:  s = w2; d = dw2; break;
            default: s = w3; d = dw3; break;
        }
        i = ((size_t)(blockIdx.x & 127) * 256 + threadIdx.x) * 8;
    }
    *(short8*)(d + i) = pack8(s + i);
}

// ---------------------------------------------------------------------------
// Projections (all three in one launch, z selects q/k/v):
// C[m][f] = sum_d X[m][d]*W[f][d] + bias[f], scaled, written bf16.
// z<2: out[hb][s][dkv] (Q scaled by log2e/8, K); z==2: out[hb][dkv][s] (V^T).
// ---------------------------------------------------------------------------
__global__ __launch_bounds__(256, 4) void k_proj3(const unsigned short* __restrict__ Xq,
                                                  const unsigned short* __restrict__ Xk,
                                                  const unsigned short* __restrict__ Xv,
                                                  const unsigned short* __restrict__ Wq,
                                                  const unsigned short* __restrict__ Wk,
                                                  const unsigned short* __restrict__ Wv,
                                                  const float* __restrict__ bq,
                                                  const float* __restrict__ bk,
                                                  const float* __restrict__ bv,
                                                  unsigned short* __restrict__ oq,
                                                  unsigned short* __restrict__ ok,
                                                  unsigned short* __restrict__ ov)
{
    const unsigned short *X, *W; const float* bias; unsigned short* out;
    float scale = 1.0f; int vtrans = 0;
    switch (blockIdx.z) {
        case 0:  X = Xq; W = Wq; bias = bq; out = oq;
                 scale = 0.125f * 1.44269504088896340736f; break;
        case 1:  X = Xk; W = Wk; bias = bk; out = ok; break;
        default: X = Xv; W = Wv; bias = bv; out = ov; vtrans = 1; break;
    }
    const int tid = threadIdx.x;
    const int l = tid & 63, w = tid >> 6;
    const int c = l & 15, g = l >> 4;
    const int m0 = blockIdx.y * 64 + w * 16;
    const int f0 = blockIdx.x * 64;
    const int arow = m0 + c;

    f32x4 acc[4] = {};
    const unsigned short* aB = X + (size_t)arow * DM;
    for (int kb = 0; kb < DM; kb += 32) {
        short8 af = ld8(aB + kb + g * 8);
#pragma unroll
        for (int n = 0; n < 4; ++n) {
            short8 bf = ld8(W + (size_t)(f0 + n * 16 + c) * DM + kb + g * 8);
            acc[n] = mfma16(af, bf, acc[n]);
        }
    }
#pragma unroll
    for (int n = 0; n < 4; ++n) {
        const int f = f0 + n * 16 + c;
        const int h = f >> 6, d = f & 63;
        const float bvv = bias[f];
#pragma unroll
        for (int r = 0; r < 4; ++r) {
            const int m = m0 + g * 4 + r;
            const int bb = m >> 11, s = m & (NS - 1);
            const int hb = h * NB + bb;
            const float v = (acc[n][r] + bvv) * scale;
            const size_t idx = vtrans ? ((size_t)(hb * DKV + d) * NS + s)
                                      : ((size_t)(hb * NS + s) * DKV + d);
            out[idx] = f2bf(v);
        }
    }
}

// ---------------------------------------------------------------------------
// Pass 1: partial softmax denominators. Barrier-free, zero LDS: K fragments
// read directly from global (L2-resident via XCD-chunked swizzle). Key dim
// split in 2 (1024 keys per block) for occupancy; partials summed in k_att.
// Lp[ks][hb*NS+q] = sum_{k in half ks} exp2(s).
// ---------------------------------------------------------------------------
__global__ __launch_bounds__(256, 4) void k_sum(const unsigned short* __restrict__ Qh,
                                                const unsigned short* __restrict__ Kh,
                                                float* __restrict__ Lp)
{
    const int tid = threadIdx.x;
    const int l = tid & 63, w = tid >> 6;
    const int c = l & 15, g = l >> 4;

    // XCD swizzle: 2048 blocks = 8 XCDs x 256 (4 hb slices each)
    const int bid = blockIdx.x;
    const int wid = (bid & 7) * 256 + (bid >> 3);
    const int hb = wid >> 6;
    const int rem = wid & 63;
    const int q0 = (rem >> 1) * 64 + w * 16;       // this wave's 16 q-rows
    const int ks = rem & 1;                        // key half

    const unsigned short* qb = Qh + ((size_t)hb * NS + q0 + c) * DKV + g * 8;
    const short8 qf0 = ld8(qb), qf1 = ld8(qb + 32);
    const unsigned short* kslice = Kh + (size_t)hb * NS * DKV + (size_t)ks * 1024 * DKV;

    float ls[4] = {0.f, 0.f, 0.f, 0.f};
    for (int kt = 0; kt < 16; ++kt) {
        const int k0 = kt * 64;
        short8 kf[4][2];
#pragma unroll
        for (int t = 0; t < 4; ++t) {
            const unsigned short* kp = kslice + (size_t)(k0 + t * 16 + c) * DKV + g * 8;
            kf[t][0] = ld8(kp); kf[t][1] = ld8(kp + 32);
        }
#pragma unroll
        for (int t = 0; t < 4; ++t) {
            f32x4 z = {};
            z = mfma16(qf0, kf[t][0], z);
            z = mfma16(qf1, kf[t][1], z);
#pragma unroll
            for (int r = 0; r < 4; ++r) ls[r] += exp2f(z[r]);
        }
    }
#pragma unroll
    for (int r = 0; r < 4; ++r) {
        float s = ls[r];
        s += __shfl_xor(s, 1);
        s += __shfl_xor(s, 2);
        s += __shfl_xor(s, 4);
        s += __shfl_xor(s, 8);
        if (c == 0) Lp[(size_t)ks * HB * NS + hb * NS + q0 + g * 4 + r] = s;
    }
}

// ---------------------------------------------------------------------------
// Pass 2: barrier-free fused attention. K and V fragments read directly from
// global (L2); per-wave 2KB LDS tile transposes P (intra-wave lgkmcnt only).
// Writes normalized attn fp32 (wide f32x4 from LDS rows) and O bf16.
// ---------------------------------------------------------------------------
__global__ __launch_bounds__(256, 4) void k_att(const unsigned short* __restrict__ Qh,
                                                const unsigned short* __restrict__ Kh,
                                                const unsigned short* __restrict__ Vt,
                                                const float* __restrict__ Lp,
                                                float* __restrict__ attn,
                                                unsigned short* __restrict__ Obuf)
{
    __shared__ __align__(16) char plds[4 * 2048];  // per-wave 16x64 bf16 P tile
    const int tid = threadIdx.x;
    const int l = tid & 63, w = tid >> 6;
    const int c = l & 15, g = l >> 4;
    constexpr int NT = NS / 64;

    // XCD swizzle: 1024 blocks = 8 XCDs x 128 (4 hb slices each)
    const int bid = blockIdx.x;
    const int wid = (bid & 7) * 128 + (bid >> 3);
    const int hb = wid >> 5;
    const int q0 = (wid & 31) * 64 + w * 16;       // this wave's 16 q-rows
    char* myp = plds + w * 2048;

    const unsigned short* kslice = Kh + (size_t)hb * NS * DKV;
    const unsigned short* vslice = Vt + (size_t)hb * DKV * NS;

    const unsigned short* qb = Qh + ((size_t)hb * NS + q0 + c) * DKV + g * 8;
    const short8 qf0 = ld8(qb), qf1 = ld8(qb + 32);

    float li[4];
#pragma unroll
    for (int r = 0; r < 4; ++r) {
        const size_t idx = (size_t)hb * NS + q0 + g * 4 + r;
        li[r] = 1.0f / (Lp[idx] + Lp[(size_t)HB * NS + idx]);
    }

    f32x4 oacc[4] = {};
    const int srow = l >> 2, sseg = l & 3;         // attn-store mapping
    float* srowp = attn + (size_t)hb * NS * NS + (size_t)(q0 + srow) * NS + sseg * 16;
    const int swsr = (srow & 7) << 4;
    const int swc = (c & 7) << 4;

    for (int kt = 0; kt < NT; ++kt) {
        const int k0 = kt * 64;
        // K and V fragments straight from global (L2-resident)
        short8 kf[4][2], vf[2][4];
#pragma unroll
        for (int t = 0; t < 4; ++t) {
            const unsigned short* kp = kslice + (size_t)(k0 + t * 16 + c) * DKV + g * 8;
            kf[t][0] = ld8(kp); kf[t][1] = ld8(kp + 32);
        }
#pragma unroll
        for (int kk = 0; kk < 2; ++kk)
#pragma unroll
            for (int n = 0; n < 4; ++n)
                vf[kk][n] = ld8(vslice + (size_t)(n * 16 + c) * NS + k0 + kk * 32 + g * 8);
        // QK^T
        f32x4 sc[4];
#pragma unroll
        for (int t = 0; t < 4; ++t) {
            f32x4 z = {};
            z = mfma16(qf0, kf[t][0], z);
            z = mfma16(qf1, kf[t][1], z);
            sc[t] = z;
        }
        // normalized P -> swizzled per-wave LDS (bf16)
#pragma unroll
        for (int t = 0; t < 4; ++t)
#pragma unroll
            for (int r = 0; r < 4; ++r) {
                const float p = exp2f(sc[t][r]) * li[r];
                const int row = g * 4 + r;
                int by = row * 128 + (t * 16 + c) * 2;
                by ^= (row & 7) << 4;
                *(unsigned short*)(myp + by) = f2bf(p);
            }
        asm volatile("s_waitcnt lgkmcnt(0)" ::: "memory");
        __builtin_amdgcn_sched_barrier(0);
        // attn store (plain f32x4; retires under the PV MFMA block)
        {
            const short8 p0 = *(const short8*)(myp + srow * 128 + ((sseg * 32) ^ swsr));
            const short8 p1 = *(const short8*)(myp + srow * 128 + ((sseg * 32 + 16) ^ swsr));
            f32x4 o0, o1, o2, o3;
#pragma unroll
            for (int j = 0; j < 4; ++j) {
                o0[j] = bf2f((unsigned short)p0[j]);
                o1[j] = bf2f((unsigned short)p0[4 + j]);
                o2[j] = bf2f((unsigned short)p1[j]);
                o3[j] = bf2f((unsigned short)p1[4 + j]);
            }
            float* dst = srowp + k0;
            *(f32x4*)(dst)      = o0;
            *(f32x4*)(dst + 4)  = o1;
            *(f32x4*)(dst + 8)  = o2;
            *(f32x4*)(dst + 12) = o3;
        }
        // PV: A-frags of P from wave LDS, B-frags of V^T from registers
#pragma unroll
        for (int kk = 0; kk < 2; ++kk) {
            const short8 pa = *(const short8*)(myp + c * 128 + ((kk * 64 + g * 16) ^ swc));
#pragma unroll
            for (int n = 0; n < 4; ++n)
                oacc[n] = mfma16(pa, vf[kk][n], oacc[n]);
        }
    }

    const int h = hb >> 2, bb = hb & 3;
#pragma unroll
    for (int n = 0; n < 4; ++n)
#pragma unroll
        for (int r = 0; r < 4; ++r) {
            const int q = q0 + g * 4 + r;
            const int dv = n * 16 + c;
            Obuf[((size_t)(bb * NS + q)) * DM + h * DKV + dv] = f2bf(oacc[n][r]);
        }
}

// ---------------------------------------------------------------------------
// FC: Y[m][d] = sum_f O[m][f]*Wfc[d][f] + bfc[d] + resid[m][d], bf16 out.
// ---------------------------------------------------------------------------
__global__ __launch_bounds__(256, 4) void k_fc(const unsigned short* __restrict__ O,
                                            const unsigned short* __restrict__ Wfc,
                                            const float* __restrict__ bfc,
                                            const float* __restrict__ resid,
                                            unsigned short* __restrict__ Y)
{
    const int tid = threadIdx.x;
    const int l = tid & 63, w = tid >> 6;
    const int c = l & 15, g = l >> 4;
    const int m0 = blockIdx.y * 64 + w * 16;
    const int f0 = blockIdx.x * 64;
    const int arow = m0 + c;

    f32x4 acc[4] = {};
    const unsigned short* aB = O + (size_t)arow * DM;
    for (int kb = 0; kb < DM; kb += 32) {
        short8 af = ld8(aB + kb + g * 8);
#pragma unroll
        for (int n = 0; n < 4; ++n) {
            short8 bf = ld8(Wfc + (size_t)(f0 + n * 16 + c) * DM + kb + g * 8);
            acc[n] = mfma16(af, bf, acc[n]);
        }
    }
#pragma unroll
    for (int n = 0; n < 4; ++n) {
        const int d = f0 + n * 16 + c;
        const float bv = bfc[d];
#pragma unroll
        for (int r = 0; r < 4; ++r) {
            const int m = m0 + g * 4 + r;
            const float v = acc[n][r] + bv + resid[(size_t)m * DM + d];
            Y[(size_t)m * DM + d] = f2bf(v);
        }
    }
}

// ---------------------------------------------------------------------------
// LayerNorm: one wave per row of 512.
// ---------------------------------------------------------------------------
__global__ __launch_bounds__(256) void k_ln(const unsigned short* __restrict__ Y,
                                            const float* __restrict__ gam,
                                            const float* __restrict__ bet,
                                            float* __restrict__ out)
{
    const int tid = threadIdx.x;
    const int l = tid & 63, w = tid >> 6;
    const int row = blockIdx.x * 4 + w;

    const short8 yv = ld8(Y + (size_t)row * DM + l * 8);
    float x[8];
#pragma unroll
    for (int j = 0; j < 8; ++j) x[j] = bf2f((unsigned short)yv[j]);

    float s = 0.f;
#pragma unroll
    for (int j = 0; j < 8; ++j) s += x[j];
#pragma unroll
    for (int mask = 1; mask <= 32; mask <<= 1) s += __shfl_xor(s, mask);
    const float mean = s * (1.0f / DM);

    float d2 = 0.f;
#pragma unroll
    for (int j = 0; j < 8; ++j) { const float t = x[j] - mean; d2 += t * t; }
#pragma unroll
    for (int mask = 1; mask <= 32; mask <<= 1) d2 += __shfl_xor(d2, mask);
    const float rstd = rsqrtf(d2 * (1.0f / DM) + 1e-5f);

#pragma unroll
    for (int j = 0; j < 8; ++j) {
        const int d = l * 8 + j;
        out[(size_t)row * DM + d] = (x[j] - mean) * rstd * gam[d] + bet[d];
    }
}

// ---------------------------------------------------------------------------
extern "C" void kernel_launch(void* const* d_in, const int* in_sizes, int n_in,
                              void* d_out, int out_size, void* d_ws, size_t ws_size,
                              hipStream_t stream)
{
    const float* q    = (const float*)d_in[0];
    const float* k    = (const float*)d_in[1];
    const float* v    = (const float*)d_in[2];
    const float* w_qs = (const float*)d_in[3];
    const float* b_qs = (const float*)d_in[4];
    const float* w_ks = (const float*)d_in[5];
    const float* b_ks = (const float*)d_in[6];
    const float* w_vs = (const float*)d_in[7];
    const float* b_vs = (const float*)d_in[8];
    const float* w_fc = (const float*)d_in[9];
    const float* b_fc = (const float*)d_in[10];
    const float* ln_g = (const float*)d_in[11];
    const float* ln_b = (const float*)d_in[12];

    char* ws = (char*)d_ws;
    unsigned short* Qh = (unsigned short*)(ws);                    //  8 MB bf16 [hb][s][64], scaled log2e/8
    unsigned short* Kh = (unsigned short*)(ws + (8u  << 20));      //  8 MB bf16 [hb][s][64]
    unsigned short* Vt = (unsigned short*)(ws + (16u << 20));      //  8 MB bf16 [hb][64][s]
    unsigned short* Ob = (unsigned short*)(ws + (24u << 20));      //  8 MB bf16 [m][512]
    unsigned short* Yb = (unsigned short*)(ws + (32u << 20));      //  8 MB bf16 [m][512]
    unsigned short* Wq = (unsigned short*)(ws + (40u << 20));      // 512 KB bf16 each
    unsigned short* Wk = Wq + (size_t)DM * DM;
    unsigned short* Wv = Wk + (size_t)DM * DM;
    unsigned short* Wf = Wv + (size_t)DM * DM;
    unsigned short* Xq = (unsigned short*)(ws + (48u << 20));      //  8 MB bf16 each
    unsigned short* Xk = (unsigned short*)(ws + (56u << 20));
    unsigned short* Xv = (unsigned short*)(ws + (64u << 20));
    float*          Lpart = (float*)(ws + (72u << 20));            // 2 x 256 KB partial denoms

    float* xout = (float*)d_out;
    float* attn = xout + (size_t)NB * NS * DM;  // output 1 region

    k_cvt<<<dim3(2048, 4), 256, 0, stream>>>(q, k, v, w_qs, w_ks, w_vs, w_fc,
                                             Xq, Xk, Xv, Wq, Wk, Wv, Wf);

    k_proj3<<<dim3(8, 128, 3), 256, 0, stream>>>(Xq, Xk, Xv, Wq, Wk, Wv,
                                                 b_qs, b_ks, b_vs, Qh, Kh, Vt);

    k_sum<<<2048, 256, 0, stream>>>(Qh, Kh, Lpart);
    k_att<<<1024, 256, 0, stream>>>(Qh, Kh, Vt, Lpart, attn, Ob);

    k_fc<<<dim3(8, 128), 256, 0, stream>>>(Ob, Wf, b_fc, q, Yb);
    k_ln<<<NB * NS / 4, 256, 0, stream>>>(Yb, ln_g, ln_b, xout);
}